// Round 1
// baseline (148.997 us; speedup 1.0000x reference)
//
#include <hip/hip_runtime.h>

#define NA 8
#define NV 16
#define NS (NA * NV)          // 128 segments
#define NW 4                  // waves per block (256 threads)
#define FIX_SHIFT 43
#define FIX_MASK ((1ULL << FIX_SHIFT) - 1)
#define FIX_SCALE 2147483648.0f   // 2^31

// ---------------------------------------------------------------------------
// K1: per-row sigmoid mean -> one packed ds_add_u64 per (row, attr).
// packed = (count=1) << 43  |  round(per_node * 2^31)
// Per-block bounds: rows/block <= 4096 -> sum field < 4096*2^31 < 2^43, ok;
// count < 2^21, ok.
// v2 changes vs previous round:
//   - nb=2048 (8 blocks/CU -> 32 waves/CU, was 16): latency-bound fix
//   - 2 rows per thread per iteration (64B contiguous per lane): 2x MLP
//   - per-wave histogram replication h[4][NS]: no cross-wave atomic serialization
// Epilogue: plain store of 128 merged partials, transposed [segment][block]
// so K2 reads coalesced. NO global atomics anywhere.
// ---------------------------------------------------------------------------

__device__ __forceinline__ float sigmoid8_mean(float4 p0, float4 p1) {
    float s = __builtin_amdgcn_rcpf(1.0f + __expf(-p0.x))
            + __builtin_amdgcn_rcpf(1.0f + __expf(-p0.y))
            + __builtin_amdgcn_rcpf(1.0f + __expf(-p0.z))
            + __builtin_amdgcn_rcpf(1.0f + __expf(-p0.w))
            + __builtin_amdgcn_rcpf(1.0f + __expf(-p1.x))
            + __builtin_amdgcn_rcpf(1.0f + __expf(-p1.y))
            + __builtin_amdgcn_rcpf(1.0f + __expf(-p1.z))
            + __builtin_amdgcn_rcpf(1.0f + __expf(-p1.w));
    return s * 0.125f;   // in (0,1)
}

__global__ __launch_bounds__(256) void k1_accum(
    const float* __restrict__ preds,           // [B, 8]
    const int*   __restrict__ attrs,           // [B, 8]
    unsigned long long* __restrict__ partials, // [NS, nb]
    int B, int nb)
{
    __shared__ unsigned long long h[NW][NS];
    for (int i = threadIdx.x; i < NW * NS; i += 256)
        ((unsigned long long*)h)[i] = 0ULL;
    __syncthreads();

    const int wave = threadIdx.x >> 6;
    unsigned long long* __restrict__ hw = h[wave];

    const int stride  = nb * 256;      // threads in grid
    const int npairs  = B >> 1;

    for (int rp = blockIdx.x * 256 + threadIdx.x; rp < npairs; rp += stride) {
        const int r0 = rp * 2;
        // 64B contiguous preds per lane (2 rows), 64B contiguous attrs
        const float4* p4 = (const float4*)(preds + (size_t)r0 * NA);
        float4 p0 = p4[0];
        float4 p1 = p4[1];
        float4 p2 = p4[2];
        float4 p3 = p4[3];
        const int4* a4 = (const int4*)(attrs + (size_t)r0 * NA);
        int4 a0 = a4[0];
        int4 a1 = a4[1];
        int4 a2 = a4[2];
        int4 a3 = a4[3];

        // row 0
        {
            float per_node = sigmoid8_mean(p0, p1);
            unsigned int fixed = (unsigned int)(per_node * FIX_SCALE);  // < 2^31
            unsigned long long add = (1ULL << FIX_SHIFT) | (unsigned long long)fixed;
            atomicAdd(&hw[0 * NV + a0.x], add);
            atomicAdd(&hw[1 * NV + a0.y], add);
            atomicAdd(&hw[2 * NV + a0.z], add);
            atomicAdd(&hw[3 * NV + a0.w], add);
            atomicAdd(&hw[4 * NV + a1.x], add);
            atomicAdd(&hw[5 * NV + a1.y], add);
            atomicAdd(&hw[6 * NV + a1.z], add);
            atomicAdd(&hw[7 * NV + a1.w], add);
        }
        // row 1
        {
            float per_node = sigmoid8_mean(p2, p3);
            unsigned int fixed = (unsigned int)(per_node * FIX_SCALE);
            unsigned long long add = (1ULL << FIX_SHIFT) | (unsigned long long)fixed;
            atomicAdd(&hw[0 * NV + a2.x], add);
            atomicAdd(&hw[1 * NV + a2.y], add);
            atomicAdd(&hw[2 * NV + a2.z], add);
            atomicAdd(&hw[3 * NV + a2.w], add);
            atomicAdd(&hw[4 * NV + a3.x], add);
            atomicAdd(&hw[5 * NV + a3.y], add);
            atomicAdd(&hw[6 * NV + a3.z], add);
            atomicAdd(&hw[7 * NV + a3.w], add);
        }
    }

    // odd-B tail: one row, handled by a single thread
    if ((B & 1) && blockIdx.x == 0 && threadIdx.x == 0) {
        const int r = B - 1;
        const float4* p4 = (const float4*)(preds + (size_t)r * NA);
        float4 p0 = p4[0];
        float4 p1 = p4[1];
        float per_node = sigmoid8_mean(p0, p1);
        unsigned int fixed = (unsigned int)(per_node * FIX_SCALE);
        unsigned long long add = (1ULL << FIX_SHIFT) | (unsigned long long)fixed;
        const int4* a4 = (const int4*)(attrs + (size_t)r * NA);
        int4 a0 = a4[0];
        int4 a1 = a4[1];
        atomicAdd(&hw[0 * NV + a0.x], add);
        atomicAdd(&hw[1 * NV + a0.y], add);
        atomicAdd(&hw[2 * NV + a0.z], add);
        atomicAdd(&hw[3 * NV + a0.w], add);
        atomicAdd(&hw[4 * NV + a1.x], add);
        atomicAdd(&hw[5 * NV + a1.y], add);
        atomicAdd(&hw[6 * NV + a1.z], add);
        atomicAdd(&hw[7 * NV + a1.w], add);
    }
    __syncthreads();

    // merge 4 per-wave copies; packed fields can't overflow (bounds above hold
    // for the whole block, so a fortiori for the sum of the 4 copies)
    if (threadIdx.x < NS) {
        unsigned long long m = h[0][threadIdx.x] + h[1][threadIdx.x]
                             + h[2][threadIdx.x] + h[3][threadIdx.x];
        partials[(size_t)threadIdx.x * nb + blockIdx.x] = m;
    }
}

// ---------------------------------------------------------------------------
// K2: one block per segment. Coalesced read of nb packed partials, unpack,
// u64/u32 accumulate, wave+LDS reduce, fp64 mean.
// ---------------------------------------------------------------------------
__global__ __launch_bounds__(256) void k2_reduce(
    const unsigned long long* __restrict__ partials, // [NS, nb]
    double* __restrict__ means,                      // [NS]
    int*    __restrict__ pres,                       // [NS]
    int nb)
{
    const int s = blockIdx.x;
    unsigned long long sum = 0ULL;
    unsigned int cnt = 0u;
    for (int b = threadIdx.x; b < nb; b += 256) {
        unsigned long long p = partials[(size_t)s * nb + b];
        cnt += (unsigned int)(p >> FIX_SHIFT);
        sum += (p & FIX_MASK);
    }
    for (int off = 32; off > 0; off >>= 1) {
        sum += __shfl_down(sum, off, 64);
        cnt += __shfl_down(cnt, off, 64);
    }
    __shared__ unsigned long long ws_[4];
    __shared__ unsigned int wc_[4];
    const int wave = threadIdx.x >> 6;
    if ((threadIdx.x & 63) == 0) { ws_[wave] = sum; wc_[wave] = cnt; }
    __syncthreads();
    if (threadIdx.x == 0) {
        unsigned long long S = ws_[0] + ws_[1] + ws_[2] + ws_[3];
        unsigned int C = wc_[0] + wc_[1] + wc_[2] + wc_[3];
        means[s] = C ? ((double)S * (1.0 / (double)FIX_SCALE)) / (double)C : 0.0;
        pres[s]  = C ? 1 : 0;
    }
}

// ---------------------------------------------------------------------------
// K3: 1 block, 128 threads. Pairwise squared diffs of means within each
// attribute (i<j, both present), fp64 reduce, scalar out.
// ---------------------------------------------------------------------------
__global__ __launch_bounds__(128) void k3_finalize(
    const double* __restrict__ means,
    const int*    __restrict__ pres,
    float* __restrict__ out)
{
    __shared__ double s_mean[NS];
    __shared__ int    s_pres[NS];
    const int t = threadIdx.x;
    s_mean[t] = means[t];
    s_pres[t] = pres[t];
    __syncthreads();

    const int a = t >> 4;
    const int i = t & (NV - 1);
    double loss = 0.0;
    int    ncmp = 0;
    if (s_pres[t]) {
        const double mi = s_mean[t];
        for (int j = i + 1; j < NV; ++j) {
            const int sj = a * NV + j;
            if (s_pres[sj]) {
                const double d = mi - s_mean[sj];
                loss += d * d;
                ncmp += 1;
            }
        }
    }
    for (int off = 32; off > 0; off >>= 1) {
        loss += __shfl_down(loss, off, 64);
        ncmp += __shfl_down(ncmp, off, 64);
    }
    __shared__ double w_loss[2];
    __shared__ int    w_ncmp[2];
    const int wave = t >> 6;
    if ((t & 63) == 0) { w_loss[wave] = loss; w_ncmp[wave] = ncmp; }
    __syncthreads();
    if (t == 0) {
        const double total = w_loss[0] + w_loss[1];
        const int    n     = w_ncmp[0] + w_ncmp[1];
        out[0] = (n > 0) ? (float)(total / (double)n) : 0.0f;
    }
}

extern "C" void kernel_launch(void* const* d_in, const int* in_sizes, int n_in,
                              void* d_out, int out_size, void* d_ws, size_t ws_size,
                              hipStream_t stream) {
    const float* preds = (const float*)d_in[0];
    const int*   attrs = (const int*)d_in[1];
    float*       out   = (float*)d_out;

    const int B = in_sizes[1] / NA;

    // Pick nb (K1 grid) by available workspace; 2048 preferred (8 blocks/CU,
    // 32 waves/CU = full occupancy). Tail: means (128 f64) + pres (128 i32).
    const size_t tail = NS * sizeof(double) + NS * sizeof(int);
    int nb = 2048;
    while (nb > 512 &&
           ws_size < (size_t)NS * nb * sizeof(unsigned long long) + tail) {
        nb >>= 1;
    }

    unsigned long long* partials = (unsigned long long*)d_ws;
    double* means = (double*)((char*)d_ws + (size_t)NS * nb * sizeof(unsigned long long));
    int*    pres  = (int*)(means + NS);

    k1_accum<<<nb, 256, 0, stream>>>(preds, attrs, partials, B, nb);
    k2_reduce<<<NS, 256, 0, stream>>>(partials, means, pres, nb);
    k3_finalize<<<1, 128, 0, stream>>>(means, pres, out);
}